// Round 16
// baseline (15389.299 us; speedup 1.0000x reference)
//
#include <hip/hip_runtime.h>

#define BB 16
#define NN 2048
#define CC 64
#define KNN 20
#define OUTC 1024

// non-fusable f32 multiply: inline-asm v_mul_f32 blocks -ffp-contract=fast
// from fusing a rounded product into a following add (numpy materializes
// rounded products at ufunc boundaries).
__device__ __forceinline__ float mul_nf(float a, float b) {
  float r;
  asm("v_mul_f32 %0, %1, %2" : "=v"(r) : "v"(a), "v"(b));
  return r;
}

// ====== xx: np.sum(f*f, -1) via DISPATCHED FLOAT_pairwise_sum, AVX512 npyv:
// n=64 -> r0..r3 = 16-lane loads of the rounded squares; vectorwise
// (r0+r1)+(r2+r3); then _mm512_reduce_add_ps tree. ======
__global__ __launch_bounds__(256) void xx32_kernel(const float* __restrict__ F,
                                                   float* __restrict__ xxf) {
  int p = blockIdx.x * 256 + threadIdx.x;
  const float* f = F + (size_t)p * CC;
  float t[64];
#pragma unroll
  for (int c = 0; c < 64; ++c) t[c] = mul_nf(f[c], f[c]);
  float v[16];
#pragma unroll
  for (int l = 0; l < 16; ++l)
    v[l] = (t[l] + t[16 + l]) + (t[32 + l] + t[48 + l]);
  float t3[8];
#pragma unroll
  for (int j = 0; j < 8; ++j) t3[j] = v[j] + v[j + 8];
  float t6[4];
#pragma unroll
  for (int k = 0; k < 4; ++k) t6[k] = t3[k] + t3[k + 4];
  xxf[p] = (t6[0] + t6[2]) + (t6[1] + t6[3]);
}

// ====== packed top-k key: monotone f32 score (hi) | inverted index (lo).
// Ties -> SMALLER index wins. ======
__device__ __forceinline__ unsigned long long packkey(float s, int m) {
  unsigned int u = __float_as_uint(s);
  u ^= (u >> 31) ? 0xFFFFFFFFu : 0x80000000u;
  return ((unsigned long long)u << 32) | (unsigned int)(NN - 1 - m);
}

#define INSERT_KEY(key)                                   \
  if ((key) > kv[KNN - 1]) {                              \
    _Pragma("unroll")                                     \
    for (int jj = KNN - 1; jj >= 1; --jj) {               \
      if ((key) > kv[jj - 1]) kv[jj] = kv[jj - 1];        \
      else if ((key) > kv[jj]) kv[jj] = (key);            \
    }                                                     \
    if ((key) > kv[0]) kv[0] = (key);                     \
  }

// ====== kNN gram: numpy c_einsum SOP, AVX512 npyv, count=64 = one vstepx4
// iteration of the chained muladd (desc blocks ab3..ab0), then reduce tree. ======
__global__ __launch_bounds__(256) void knn_fast(const float* __restrict__ F,
                                                const float* __restrict__ xxf,
                                                int* __restrict__ idx) {
  __shared__ __align__(16) char smem[52736];
  float* SQ = (float*)smem;                   // [64 row][68] row-major
  float* SP = (float*)(smem + 17408);         // [64 row][68]
  float* SS = (float*)(smem + 34816);         // [64 row][68]
  float* xq = (float*)(smem + 52224);
  float* xp = (float*)(smem + 52480);

  int b = blockIdx.y, n0 = blockIdx.x * 64, t = threadIdx.x;
  const float* fb = F + (size_t)b * NN * CC;

#pragma unroll
  for (int j = 0; j < 4; ++j) {
    int v = t + 256 * j;
    int row = v >> 4, c4 = (v & 15) * 4;
    *(float4*)&SQ[row * 68 + c4] = *(const float4*)(fb + (size_t)(n0 + row) * CC + c4);
  }
  if (t < 64) xq[t] = xxf[b * NN + n0 + t];

  unsigned long long kv[KNN];
#pragma unroll
  for (int k = 0; k < KNN; ++k) kv[k] = 0ull;

  int tx = t & 7, ty = t >> 3;   // gram mapping: 2 queries x 2 m per thread
  int q0 = ty * 2;
  int r = t & 63, qq = t >> 6;   // insertion mapping

  for (int m0 = 0; m0 < NN; m0 += 64) {
    __syncthreads();
#pragma unroll
    for (int j = 0; j < 4; ++j) {
      int v = t + 256 * j;
      int row = v >> 4, c4 = (v & 15) * 4;
      *(float4*)&SP[row * 68 + c4] = *(const float4*)(fb + (size_t)(m0 + row) * CC + c4);
    }
    if (t < 64) xp[t] = xxf[b * NN + m0 + t];
    __syncthreads();

#pragma unroll 1
    for (int p = 0; p < 4; ++p) {
      int mt = p * 16 + tx * 2;
      float ln[4][16];  // [qi*2+mi][lane]
#pragma unroll
      for (int dd = 0; dd < 4; ++dd) {
        int cc = (3 - dd) * 16;  // descending 16-blocks: numpy ab3..ab0 chain
#pragma unroll
        for (int g = 0; g < 4; ++g) {
          float4 a0 = *(const float4*)&SQ[q0 * 68 + cc + g * 4];
          float4 a1 = *(const float4*)&SQ[(q0 + 1) * 68 + cc + g * 4];
          float4 c0 = *(const float4*)&SP[mt * 68 + cc + g * 4];
          float4 c1 = *(const float4*)&SP[(mt + 1) * 68 + cc + g * 4];
          float av0[4] = {a0.x, a0.y, a0.z, a0.w};
          float av1[4] = {a1.x, a1.y, a1.z, a1.w};
          float bv0[4] = {c0.x, c0.y, c0.z, c0.w};
          float bv1[4] = {c1.x, c1.y, c1.z, c1.w};
#pragma unroll
          for (int e = 0; e < 4; ++e) {
            int l = g * 4 + e;
            if (dd == 0) {
              ln[0][l] = mul_nf(av0[e], bv0[e]);
              ln[1][l] = mul_nf(av0[e], bv1[e]);
              ln[2][l] = mul_nf(av1[e], bv0[e]);
              ln[3][l] = mul_nf(av1[e], bv1[e]);
            } else {
              ln[0][l] = fmaf(av0[e], bv0[e], ln[0][l]);
              ln[1][l] = fmaf(av0[e], bv1[e], ln[1][l]);
              ln[2][l] = fmaf(av1[e], bv0[e], ln[2][l]);
              ln[3][l] = fmaf(av1[e], bv1[e], ln[3][l]);
            }
          }
        }
      }
      // _mm512_reduce_add_ps tree
#pragma unroll
      for (int pp = 0; pp < 4; ++pp) {
        float t3[8];
#pragma unroll
        for (int j = 0; j < 8; ++j) t3[j] = ln[pp][j + 8] + ln[pp][j];
        float t6_0 = t3[4] + t3[0], t6_1 = t3[5] + t3[1];
        float t6_2 = t3[6] + t3[2], t6_3 = t3[7] + t3[3];
        float t8_0 = t6_0 + t6_2, t8_1 = t6_1 + t6_3;
        float s = t8_0 + t8_1;
        int qi = pp >> 1, mi = pp & 1;
        float sv = (2.0f * s - xq[q0 + qi]) - xp[mt + mi];
        SS[(q0 + qi) * 68 + mt + mi] = sv;
      }
    }
    __syncthreads();

#pragma unroll
    for (int j4 = 0; j4 < 4; ++j4) {
      float4 sv = *(const float4*)&SS[r * 68 + qq * 16 + j4 * 4];
      int mb = m0 + qq * 16 + j4 * 4;
      unsigned long long k0 = packkey(sv.x, mb + 0);
      INSERT_KEY(k0)
      unsigned long long k1 = packkey(sv.y, mb + 1);
      INSERT_KEY(k1)
      unsigned long long k2 = packkey(sv.z, mb + 2);
      INSERT_KEY(k2)
      unsigned long long k3 = packkey(sv.w, mb + 3);
      INSERT_KEY(k3)
    }
  }

  __syncthreads();
  unsigned long long* keys = (unsigned long long*)smem;
#pragma unroll
  for (int k = 0; k < KNN; ++k) keys[t * KNN + k] = kv[k];
  __syncthreads();
  if (t < 64) {
    for (int q2 = 1; q2 < 4; ++q2) {
      int base = (q2 * 64 + t) * KNN;
#pragma unroll 1
      for (int k = 0; k < KNN; ++k) {
        unsigned long long key = keys[base + k];
        if (key <= kv[KNN - 1]) break;
        INSERT_KEY(key)
      }
    }
    int* dst = idx + (size_t)(b * NN + n0 + t) * KNN;
#pragma unroll
    for (int k = 0; k < KNN; ++k)
      dst[k] = (NN - 1) - (int)(unsigned int)(kv[k] & 0xFFFFFFFFull);
  }
}

// ====== h(edge)·W, einsum count=128 = two chained vstepx4 iterations
// (desc blocks within each iteration), then the 16-lane reduce tree.
// Chains BIT-IDENTICAL to R11/R15; center row fv now read from LDS
// (broadcast — all o-lanes same address, conflict-free) to cut VGPRs. ======
#define EDGE_H_NP(ln, fp, fnp, w0, w1, OUTVAR)                                  \
  {                                                                             \
    _Pragma("unroll")                                                           \
    for (int dd = 0; dd < 4; ++dd) {                                            \
      int c4b = (3 - dd) * 4;                                                   \
      _Pragma("unroll")                                                         \
      for (int g = 0; g < 4; ++g) {                                             \
        int c4 = c4b + g;                                                       \
        float4 fm = *(const float4*)(fp + c4 * 4);                              \
        float4 fv = *(const float4*)(fnp + c4 * 4);                             \
        float4 wv = w0[c4];                                                     \
        float e0 = fm.x - fv.x, e1 = fm.y - fv.y;                               \
        float e2 = fm.z - fv.z, e3 = fm.w - fv.w;                               \
        int l = g * 4;                                                          \
        if (dd == 0) {                                                          \
          ln[l + 0] = mul_nf(e0, wv.x); ln[l + 1] = mul_nf(e1, wv.y);           \
          ln[l + 2] = mul_nf(e2, wv.z); ln[l + 3] = mul_nf(e3, wv.w);           \
        } else {                                                                \
          ln[l + 0] = fmaf(e0, wv.x, ln[l + 0]);                                \
          ln[l + 1] = fmaf(e1, wv.y, ln[l + 1]);                                \
          ln[l + 2] = fmaf(e2, wv.z, ln[l + 2]);                                \
          ln[l + 3] = fmaf(e3, wv.w, ln[l + 3]);                                \
        }                                                                       \
      }                                                                         \
    }                                                                           \
    _Pragma("unroll")                                                           \
    for (int dd = 0; dd < 4; ++dd) {                                            \
      int c4b = (3 - dd) * 4;                                                   \
      _Pragma("unroll")                                                         \
      for (int g = 0; g < 4; ++g) {                                             \
        int c4 = c4b + g;                                                       \
        float4 fv = *(const float4*)(fnp + c4 * 4);                             \
        float4 wv = w1[c4];                                                     \
        int l = g * 4;                                                          \
        ln[l + 0] = fmaf(fv.x, wv.x, ln[l + 0]);                                \
        ln[l + 1] = fmaf(fv.y, wv.y, ln[l + 1]);                                \
        ln[l + 2] = fmaf(fv.z, wv.z, ln[l + 2]);                                \
        ln[l + 3] = fmaf(fv.w, wv.w, ln[l + 3]);                                \
      }                                                                         \
    }                                                                           \
    float t3_[8];                                                               \
    _Pragma("unroll")                                                           \
    for (int j = 0; j < 8; ++j) t3_[j] = ln[j + 8] + ln[j];                     \
    float t6_0 = t3_[4] + t3_[0], t6_1 = t3_[5] + t3_[1];                       \
    float t6_2 = t3_[6] + t3_[2], t6_3 = t3_[7] + t3_[3];                       \
    float t8_0 = t6_0 + t6_2, t8_1 = t6_1 + t6_3;                               \
    OUTVAR = t8_0 + t8_1;                                                       \
  }

// ====== EdgeConv stats: single-edge chains; per-(n,o) running hmax/hmin
// (monotone BN+leaky commutes with extremum — bit-exact). fv from LDS
// broadcast + launch_bounds(256,3) -> >=3 waves/SIMD for latency hiding. ======
template <int CACHE>
__global__ __launch_bounds__(256, 3) void stats_k(const float* __restrict__ F,
                                                  const float* __restrict__ W,
                                                  const int* __restrict__ idx,
                                                  double* __restrict__ sums,
                                                  float* __restrict__ hmm) {
  __shared__ float Fn[64 * 64];
  __shared__ double rs[256], rss[256];
  int b = blockIdx.y, n0 = blockIdx.x * 64, t = threadIdx.x;
  int o = t & 63, g4 = t >> 6;
#pragma unroll
  for (int j = 0; j < 4; ++j) {
    int v = t + 256 * j;
    int row = v >> 4, c4 = (v & 15) * 4;
    *(float4*)&Fn[row * 64 + c4] =
        *(const float4*)(F + ((size_t)(b * NN + n0 + row)) * CC + c4);
  }
  float4 w0[16], w1[16];
  const float* wp = W + o * 128;
#pragma unroll
  for (int c4 = 0; c4 < 16; ++c4) {
    w0[c4] = *(const float4*)(wp + c4 * 4);
    w1[c4] = *(const float4*)(wp + 64 + c4 * 4);
  }
  __syncthreads();
  double s = 0.0, ss = 0.0;
  for (int i = 0; i < 16; ++i) {
    int n = n0 + g4 * 16 + i;
    const float* fnp = &Fn[(g4 * 16 + i) * 64];
    const int* ip = idx + ((size_t)(b * NN + n)) * KNN;
    float hmx = -3.0e38f, hmn = 3.0e38f;
#pragma unroll 1
    for (int k = 0; k < KNN; ++k) {
      const float* fp = F + ((size_t)(b * NN + ip[k])) * CC;
      float ln[16];
      float a0;
      EDGE_H_NP(ln, fp, fnp, w0, w1, a0)
      s += (double)a0;
      ss += (double)a0 * (double)a0;
      if (CACHE) {
        hmx = fmaxf(hmx, a0);
        hmn = fminf(hmn, a0);
      }
    }
    if (CACHE) {
      size_t base = ((size_t)(b * NN + n)) * CC + o;
      hmm[base] = hmx;
      hmm[(size_t)BB * NN * CC + base] = hmn;
    }
  }
  rs[t] = s; rss[t] = ss;
  __syncthreads();
  if (t < 64) {
    double a = rs[t] + rs[t + 64] + rs[t + 128] + rs[t + 192];
    double q = rss[t] + rss[t + 64] + rss[t + 128] + rss[t + 192];
    atomicAdd(&sums[o], a);
    atomicAdd(&sums[64 + o], q);
  }
}

// ====== BN finalize for edge layers: f64 stats -> f32 mean + f32 rs ======
__global__ void finalize_np(const double* __restrict__ sums, double cntinv,
                            float* __restrict__ mrs) {
  int c = threadIdx.x;  // 64
  double mean = sums[c] * cntinv;
  double var = sums[64 + c] * cntinv - mean * mean;
  mrs[c] = (float)mean;
  mrs[64 + c] = 1.0f / sqrtf((float)var + 1e-5f);
}

// ====== apply (fused extremum): y = leaky(((h*-m)*rs)*g + b), where
// h* = hmax if g>=0 else hmin. Same unfused chain as the per-k version. ======
__global__ __launch_bounds__(256) void apply_lite(const float* __restrict__ hmm,
                                                  const float* __restrict__ mrs,
                                                  const float* __restrict__ gv,
                                                  const float* __restrict__ bvv,
                                                  float* __restrict__ Fo) {
  size_t i = (size_t)blockIdx.x * 256 + threadIdx.x;
  int o = (int)(i & 63);
  float gg = gv[o];
  float h = (gg >= 0.f) ? hmm[i] : hmm[(size_t)BB * NN * CC + i];
  float d = h - mrs[o];
  d = mul_nf(d, mrs[64 + o]);
  d = mul_nf(d, gg);
  float y = d + bvv[o];
  y = y >= 0.f ? y : 0.2f * y;
  Fo[i] = y;
}

// ====== apply (recompute fallback, no-cache path) ======
__global__ __launch_bounds__(256) void apply_rec(const float* __restrict__ F,
                                                 const float* __restrict__ W,
                                                 const int* __restrict__ idx,
                                                 const float* __restrict__ mrs,
                                                 const float* __restrict__ gv,
                                                 const float* __restrict__ bvv,
                                                 float* __restrict__ Fo) {
  __shared__ float Fn[64 * 64];
  int b = blockIdx.y, n0 = blockIdx.x * 64, t = threadIdx.x;
  int o = t & 63, g4 = t >> 6;
#pragma unroll
  for (int j = 0; j < 4; ++j) {
    int v = t + 256 * j;
    int row = v >> 4, c4 = (v & 15) * 4;
    *(float4*)&Fn[row * 64 + c4] =
        *(const float4*)(F + ((size_t)(b * NN + n0 + row)) * CC + c4);
  }
  float4 w0[16], w1[16];
  const float* wp = W + o * 128;
#pragma unroll
  for (int c4 = 0; c4 < 16; ++c4) {
    w0[c4] = *(const float4*)(wp + c4 * 4);
    w1[c4] = *(const float4*)(wp + 64 + c4 * 4);
  }
  __syncthreads();
  float m32 = mrs[o], rs32 = mrs[64 + o];
  float gg = gv[o], bb = bvv[o];
  for (int i = 0; i < 16; ++i) {
    int n = n0 + g4 * 16 + i;
    const float* fnp = &Fn[(g4 * 16 + i) * 64];
    const int* ip = idx + ((size_t)(b * NN + n)) * KNN;
    float mx = -3.0e38f;
#pragma unroll 1
    for (int k = 0; k < KNN; ++k) {
      const float* fp = F + ((size_t)(b * NN + ip[k])) * CC;
      float ln[16];
      float a0;
      EDGE_H_NP(ln, fp, fnp, w0, w1, a0)
      float d0 = a0 - m32; d0 = mul_nf(d0, rs32); d0 = mul_nf(d0, gg);
      float y0 = d0 + bb;
      y0 = y0 >= 0.f ? y0 : 0.2f * y0;
      mx = fmaxf(mx, y0);
    }
    Fo[((size_t)(b * NN + n)) * CC + o] = mx;
  }
}

// ====== final stats: register-blocked GEMM, 64x64 tile (value-only) ======
template <int CACHE>
__global__ __launch_bounds__(256) void fstats_gemm(const float* __restrict__ F1,
                                                   const float* __restrict__ F2,
                                                   const float* __restrict__ F3,
                                                   const float* __restrict__ Wf,
                                                   double* __restrict__ sums,
                                                   float* __restrict__ hout) {
  __shared__ __align__(16) char smem[34816];
  float* Ft = (float*)smem;                  // [64 c][68 n]
  float* Wt = (float*)(smem + 17408);        // [64 c][68 o]
  int o0 = blockIdx.x * 64;
  int r0 = blockIdx.y * 64;  // flat row = b*NN+n
  int t = threadIdx.x;
  int to = t & 15, tn = t >> 4;
  const float* fs[3] = {F1, F2, F3};

  float acc[4][4] = {};
#pragma unroll 1
  for (int ch = 0; ch < 3; ++ch) {
    __syncthreads();
#pragma unroll
    for (int j = 0; j < 16; ++j) {
      int v = t + 256 * j;
      int oo = v >> 6, c = v & 63;
      Wt[c * 68 + oo] = Wf[(size_t)(o0 + oo) * 192 + ch * 64 + c];
    }
#pragma unroll
    for (int j = 0; j < 4; ++j) {
      int v = t + 256 * j;
      int row = v >> 4, c4 = (v & 15) * 4;
      float4 val = *(const float4*)(fs[ch] + ((size_t)(r0 + row)) * CC + c4);
      Ft[(c4 + 0) * 68 + row] = val.x;
      Ft[(c4 + 1) * 68 + row] = val.y;
      Ft[(c4 + 2) * 68 + row] = val.z;
      Ft[(c4 + 3) * 68 + row] = val.w;
    }
    __syncthreads();
#pragma unroll 8
    for (int c = 0; c < 64; ++c) {
      float4 av = *(const float4*)&Ft[c * 68 + tn * 4];
      float4 wv = *(const float4*)&Wt[c * 68 + to * 4];
      float a[4] = {av.x, av.y, av.z, av.w};
      float w[4] = {wv.x, wv.y, wv.z, wv.w};
#pragma unroll
      for (int i = 0; i < 4; ++i)
#pragma unroll
        for (int j = 0; j < 4; ++j) acc[i][j] = fmaf(a[i], w[j], acc[i][j]);
    }
  }
  if (CACHE) {
#pragma unroll
    for (int i = 0; i < 4; ++i) {
      float4 hv = {acc[i][0], acc[i][1], acc[i][2], acc[i][3]};
      *(float4*)&hout[((size_t)(r0 + tn * 4 + i)) * OUTC + o0 + to * 4] = hv;
    }
  }
  double sj[4], ssj[4];
#pragma unroll
  for (int j = 0; j < 4; ++j) {
    sj[j] = 0.0; ssj[j] = 0.0;
#pragma unroll
    for (int i = 0; i < 4; ++i) {
      sj[j] += (double)acc[i][j];
      ssj[j] += (double)acc[i][j] * (double)acc[i][j];
    }
  }
  __syncthreads();
  double* reds = (double*)smem;            // [64 o][16 tn]
  double* redss = (double*)(smem + 8192);
#pragma unroll
  for (int j = 0; j < 4; ++j) {
    reds[(to * 4 + j) * 16 + tn] = sj[j];
    redss[(to * 4 + j) * 16 + tn] = ssj[j];
  }
  __syncthreads();
  if (t < 64) {
    double s = 0.0, ss = 0.0;
#pragma unroll
    for (int u = 0; u < 16; ++u) {
      s += reds[t * 16 + u];
      ss += redss[t * 16 + u];
    }
    atomicAdd(&sums[o0 + t], s);
    atomicAdd(&sums[1024 + o0 + t], ss);
  }
}

// ====== BN finalize (final layer): f64 math -> f32 sc/sh ======
__global__ void finalize_f(const double* __restrict__ sums,
                           const float* __restrict__ g,
                           const float* __restrict__ bb, double cntinv,
                           float* __restrict__ scsh) {
  int c = blockIdx.x * 256 + threadIdx.x;  // 1024
  double mean = sums[c] * cntinv;
  double var = sums[1024 + c] * cntinv - mean * mean;
  double sc = (double)g[c] / sqrt(var + 1e-5);
  scsh[c] = (float)sc;
  scsh[1024 + c] = (float)((double)bb[c] - mean * sc);
}

// ====== final apply from h cache: normalize + partial max over n chunk ======
__global__ __launch_bounds__(256) void fapply_stream(const float* __restrict__ hin,
                                                     const float* __restrict__ scsh,
                                                     float* __restrict__ pmax) {
  int b = blockIdx.y, t = threadIdx.x;
  int o = blockIdx.x * 256 + t;
  int nbase = blockIdx.z * (NN / 8);
  float sc = scsh[o], sh = scsh[1024 + o];
  float mx = -3.0e38f;
  const float* hp = hin + ((size_t)(b * NN + nbase)) * OUTC + o;
#pragma unroll 4
  for (int n = 0; n < NN / 8; ++n) {
    float y = fmaf(sc, hp[(size_t)n * OUTC], sh);
    y = y >= 0.f ? y : 0.2f * y;
    mx = fmaxf(mx, y);
  }
  pmax[((size_t)blockIdx.z * BB + b) * OUTC + o] = mx;
}

__global__ __launch_bounds__(256) void freduce(const float* __restrict__ pmax,
                                               float* __restrict__ out) {
  int v = blockIdx.x * 256 + threadIdx.x;  // b*OUTC+o
  float mx = -3.0e38f;
#pragma unroll
  for (int ch = 0; ch < 8; ++ch) mx = fmaxf(mx, pmax[(size_t)ch * BB * OUTC + v]);
  out[v] = mx;
}

// ====== fallback final apply (no cache) ======
__global__ __launch_bounds__(256) void fapply32(const float* __restrict__ F1,
                                                const float* __restrict__ F2,
                                                const float* __restrict__ F3,
                                                const float* __restrict__ Wf,
                                                const float* __restrict__ scsh,
                                                float* __restrict__ out) {
  __shared__ float Wl[64 * 193];
  __shared__ float redm[4][64];
  int b = blockIdx.y, o0 = blockIdx.x * 64, t = threadIdx.x;
  for (int j = 0; j < 48; ++j) {
    int v = t + 256 * j;
    int oo = v / 192, c = v - oo * 192;
    Wl[oo * 193 + c] = Wf[(size_t)(o0 + oo) * 192 + c];
  }
  __syncthreads();
  int o = t & 63, g = t >> 6;
  float sc = scsh[o0 + o], sh = scsh[1024 + o0 + o];
  const float* fs[3] = {F1, F2, F3};
  float mx = -3.0e38f;
  for (int n0 = 0; n0 < NN; n0 += 16) {
    int n = n0 + g * 4;
    float h[4] = {0.f, 0.f, 0.f, 0.f};
#pragma unroll
    for (int part = 0; part < 3; ++part) {
      const float* src = fs[part] + ((size_t)(b * NN + n)) * CC;
      const float* wp = &Wl[o * 193 + part * 64];
#pragma unroll 4
      for (int c4 = 0; c4 < 16; ++c4) {
        float4 w4 = {wp[c4 * 4], wp[c4 * 4 + 1], wp[c4 * 4 + 2], wp[c4 * 4 + 3]};
#pragma unroll
        for (int i = 0; i < 4; ++i) {
          float4 v = *(const float4*)(src + (size_t)i * CC + c4 * 4);
          h[i] = fmaf(w4.x, v.x, h[i]);
          h[i] = fmaf(w4.y, v.y, h[i]);
          h[i] = fmaf(w4.z, v.z, h[i]);
          h[i] = fmaf(w4.w, v.w, h[i]);
        }
      }
    }
#pragma unroll
    for (int i = 0; i < 4; ++i) {
      float y = fmaf(sc, h[i], sh);
      y = y >= 0.f ? y : 0.2f * y;
      mx = fmaxf(mx, y);
    }
  }
  redm[g][o] = mx;
  __syncthreads();
  if (t < 64) {
    float m = fmaxf(fmaxf(redm[0][o], redm[1][o]), fmaxf(redm[2][o], redm[3][o]));
    out[(size_t)b * OUTC + o0 + o] = m;
  }
}

extern "C" void kernel_launch(void* const* d_in, const int* in_sizes, int n_in,
                              void* d_out, int out_size, void* d_ws, size_t ws_size,
                              hipStream_t stream) {
  (void)in_sizes; (void)n_in; (void)out_size;
  const float* x  = (const float*)d_in[0];
  const float* W1 = (const float*)d_in[1];
  const float* g1 = (const float*)d_in[2];
  const float* b1 = (const float*)d_in[3];
  const float* W2 = (const float*)d_in[4];
  const float* g2 = (const float*)d_in[5];
  const float* b2 = (const float*)d_in[6];
  const float* W3 = (const float*)d_in[7];
  const float* g3 = (const float*)d_in[8];
  const float* b3 = (const float*)d_in[9];
  const float* Wf = (const float*)d_in[10];
  const float* gf = (const float*)d_in[11];
  const float* bf = (const float*)d_in[12];
  float* out = (float*)d_out;

  char* wsb = (char*)d_ws;
  float* F1f    = (float*)(wsb + 0);           // 8 MB
  float* F2f    = (float*)(wsb + 8388608);     // 8 MB
  float* F3f    = (float*)(wsb + 16777216);    // 8 MB
  float* xxf    = (float*)(wsb + 25165824);    // 128 KB
  int* idx      = (int*)(wsb + 25296896);      // 2.62 MB
  double* sumsd = (double*)(wsb + 27918336);   // 128 doubles
  double* fsums = (double*)(wsb + 27920384);   // 2048 doubles
  float* fscsh  = (float*)(wsb + 27936768);    // 2048 floats
  float* mrs    = (float*)(wsb + 27944960);    // 128 floats
  float* pmax   = (float*)(wsb + 27945984);    // 512 KB
  float* hmmb   = (float*)(wsb + 29360128);    // 16.78 MB (hmax+hmin planes)
  float* hbuf   = (float*)(wsb + 29360128 + 16777216);  // 134.2 MB final h
  const bool cache = ws_size >= (size_t)29360128 + (size_t)BB * NN * KNN * 64 * 4;

  const float* Fin[3] = {x, F1f, F2f};
  float* Fout[3] = {F1f, F2f, F3f};
  const float* Ws[3] = {W1, W2, W3};
  const float* gs[3] = {g1, g2, g3};
  const float* bs[3] = {b1, b2, b3};

  for (int L = 0; L < 3; ++L) {
    xx32_kernel<<<dim3(BB * NN / 256), 256, 0, stream>>>(Fin[L], xxf);
    knn_fast<<<dim3(NN / 64, BB), 256, 0, stream>>>(Fin[L], xxf, idx);
    hipMemsetAsync(sumsd, 0, 128 * sizeof(double), stream);
    if (cache) {
      stats_k<1><<<dim3(NN / 64, BB), 256, 0, stream>>>(Fin[L], Ws[L], idx, sumsd, hmmb);
      finalize_np<<<1, 64, 0, stream>>>(sumsd, 1.0 / (double)(BB * NN * KNN), mrs);
      apply_lite<<<dim3(BB * NN * CC / 256), 256, 0, stream>>>(hmmb, mrs, gs[L], bs[L],
                                                               Fout[L]);
    } else {
      stats_k<0><<<dim3(NN / 64, BB), 256, 0, stream>>>(Fin[L], Ws[L], idx, sumsd, nullptr);
      finalize_np<<<1, 64, 0, stream>>>(sumsd, 1.0 / (double)(BB * NN * KNN), mrs);
      apply_rec<<<dim3(NN / 64, BB), 256, 0, stream>>>(Fin[L], Ws[L], idx, mrs,
                                                       gs[L], bs[L], Fout[L]);
    }
  }
  hipMemsetAsync(fsums, 0, 2048 * sizeof(double), stream);
  if (cache) {
    fstats_gemm<1><<<dim3(OUTC / 64, BB * NN / 64), 256, 0, stream>>>(F1f, F2f, F3f,
                                                                      Wf, fsums, hbuf);
    finalize_f<<<4, 256, 0, stream>>>(fsums, gf, bf, 1.0 / (double)(BB * NN), fscsh);
    fapply_stream<<<dim3(OUTC / 256, BB, 8), 256, 0, stream>>>(hbuf, fscsh, pmax);
    freduce<<<dim3(BB * OUTC / 256), 256, 0, stream>>>(pmax, out);
  } else {
    fstats_gemm<0><<<dim3(OUTC / 64, BB * NN / 64), 256, 0, stream>>>(F1f, F2f, F3f,
                                                                      Wf, fsums, nullptr);
    finalize_f<<<4, 256, 0, stream>>>(fsums, gf, bf, 1.0 / (double)(BB * NN), fscsh);
    fapply32<<<dim3(OUTC / 64, BB), 256, 0, stream>>>(F1f, F2f, F3f, Wf, fscsh, out);
  }
}

// Round 17
// 3738.144 us; speedup vs baseline: 4.1168x; 4.1168x over previous
//
#include <hip/hip_runtime.h>

#define BB 16
#define NN 2048
#define CC 64
#define KNN 20
#define OUTC 1024

// non-fusable f32 multiply: inline-asm v_mul_f32 blocks -ffp-contract=fast
// from fusing a rounded product into a following add (numpy materializes
// rounded products at ufunc boundaries).
__device__ __forceinline__ float mul_nf(float a, float b) {
  float r;
  asm("v_mul_f32 %0, %1, %2" : "=v"(r) : "v"(a), "v"(b));
  return r;
}

// ====== xx: np.sum(f*f, -1) via DISPATCHED FLOAT_pairwise_sum, AVX512 npyv:
// n=64 -> r0..r3 = 16-lane loads of the rounded squares; vectorwise
// (r0+r1)+(r2+r3); then _mm512_reduce_add_ps tree. ======
__global__ __launch_bounds__(256) void xx32_kernel(const float* __restrict__ F,
                                                   float* __restrict__ xxf) {
  int p = blockIdx.x * 256 + threadIdx.x;
  const float* f = F + (size_t)p * CC;
  float t[64];
#pragma unroll
  for (int c = 0; c < 64; ++c) t[c] = mul_nf(f[c], f[c]);
  float v[16];
#pragma unroll
  for (int l = 0; l < 16; ++l)
    v[l] = (t[l] + t[16 + l]) + (t[32 + l] + t[48 + l]);
  float t3[8];
#pragma unroll
  for (int j = 0; j < 8; ++j) t3[j] = v[j] + v[j + 8];
  float t6[4];
#pragma unroll
  for (int k = 0; k < 4; ++k) t6[k] = t3[k] + t3[k + 4];
  xxf[p] = (t6[0] + t6[2]) + (t6[1] + t6[3]);
}

// ====== packed top-k key: monotone f32 score (hi) | inverted index (lo).
// Ties -> SMALLER index wins. ======
__device__ __forceinline__ unsigned long long packkey(float s, int m) {
  unsigned int u = __float_as_uint(s);
  u ^= (u >> 31) ? 0xFFFFFFFFu : 0x80000000u;
  return ((unsigned long long)u << 32) | (unsigned int)(NN - 1 - m);
}

#define INSERT_KEY(key)                                   \
  if ((key) > kv[KNN - 1]) {                              \
    _Pragma("unroll")                                     \
    for (int jj = KNN - 1; jj >= 1; --jj) {               \
      if ((key) > kv[jj - 1]) kv[jj] = kv[jj - 1];        \
      else if ((key) > kv[jj]) kv[jj] = (key);            \
    }                                                     \
    if ((key) > kv[0]) kv[0] = (key);                     \
  }

// ====== kNN gram: numpy c_einsum SOP, AVX512 npyv, count=64 = one vstepx4
// iteration of the chained muladd (desc blocks ab3..ab0), then reduce tree. ======
__global__ __launch_bounds__(256) void knn_fast(const float* __restrict__ F,
                                                const float* __restrict__ xxf,
                                                int* __restrict__ idx) {
  __shared__ __align__(16) char smem[52736];
  float* SQ = (float*)smem;                   // [64 row][68] row-major
  float* SP = (float*)(smem + 17408);         // [64 row][68]
  float* SS = (float*)(smem + 34816);         // [64 row][68]
  float* xq = (float*)(smem + 52224);
  float* xp = (float*)(smem + 52480);

  int b = blockIdx.y, n0 = blockIdx.x * 64, t = threadIdx.x;
  const float* fb = F + (size_t)b * NN * CC;

#pragma unroll
  for (int j = 0; j < 4; ++j) {
    int v = t + 256 * j;
    int row = v >> 4, c4 = (v & 15) * 4;
    *(float4*)&SQ[row * 68 + c4] = *(const float4*)(fb + (size_t)(n0 + row) * CC + c4);
  }
  if (t < 64) xq[t] = xxf[b * NN + n0 + t];

  unsigned long long kv[KNN];
#pragma unroll
  for (int k = 0; k < KNN; ++k) kv[k] = 0ull;

  int tx = t & 7, ty = t >> 3;   // gram mapping: 2 queries x 2 m per thread
  int q0 = ty * 2;
  int r = t & 63, qq = t >> 6;   // insertion mapping

  for (int m0 = 0; m0 < NN; m0 += 64) {
    __syncthreads();
#pragma unroll
    for (int j = 0; j < 4; ++j) {
      int v = t + 256 * j;
      int row = v >> 4, c4 = (v & 15) * 4;
      *(float4*)&SP[row * 68 + c4] = *(const float4*)(fb + (size_t)(m0 + row) * CC + c4);
    }
    if (t < 64) xp[t] = xxf[b * NN + m0 + t];
    __syncthreads();

#pragma unroll 1
    for (int p = 0; p < 4; ++p) {
      int mt = p * 16 + tx * 2;
      float ln[4][16];  // [qi*2+mi][lane]
#pragma unroll
      for (int dd = 0; dd < 4; ++dd) {
        int cc = (3 - dd) * 16;  // descending 16-blocks: numpy ab3..ab0 chain
#pragma unroll
        for (int g = 0; g < 4; ++g) {
          float4 a0 = *(const float4*)&SQ[q0 * 68 + cc + g * 4];
          float4 a1 = *(const float4*)&SQ[(q0 + 1) * 68 + cc + g * 4];
          float4 c0 = *(const float4*)&SP[mt * 68 + cc + g * 4];
          float4 c1 = *(const float4*)&SP[(mt + 1) * 68 + cc + g * 4];
          float av0[4] = {a0.x, a0.y, a0.z, a0.w};
          float av1[4] = {a1.x, a1.y, a1.z, a1.w};
          float bv0[4] = {c0.x, c0.y, c0.z, c0.w};
          float bv1[4] = {c1.x, c1.y, c1.z, c1.w};
#pragma unroll
          for (int e = 0; e < 4; ++e) {
            int l = g * 4 + e;
            if (dd == 0) {
              ln[0][l] = mul_nf(av0[e], bv0[e]);
              ln[1][l] = mul_nf(av0[e], bv1[e]);
              ln[2][l] = mul_nf(av1[e], bv0[e]);
              ln[3][l] = mul_nf(av1[e], bv1[e]);
            } else {
              ln[0][l] = fmaf(av0[e], bv0[e], ln[0][l]);
              ln[1][l] = fmaf(av0[e], bv1[e], ln[1][l]);
              ln[2][l] = fmaf(av1[e], bv0[e], ln[2][l]);
              ln[3][l] = fmaf(av1[e], bv1[e], ln[3][l]);
            }
          }
        }
      }
      // _mm512_reduce_add_ps tree
#pragma unroll
      for (int pp = 0; pp < 4; ++pp) {
        float t3[8];
#pragma unroll
        for (int j = 0; j < 8; ++j) t3[j] = ln[pp][j + 8] + ln[pp][j];
        float t6_0 = t3[4] + t3[0], t6_1 = t3[5] + t3[1];
        float t6_2 = t3[6] + t3[2], t6_3 = t3[7] + t3[3];
        float t8_0 = t6_0 + t6_2, t8_1 = t6_1 + t6_3;
        float s = t8_0 + t8_1;
        int qi = pp >> 1, mi = pp & 1;
        float sv = (2.0f * s - xq[q0 + qi]) - xp[mt + mi];
        SS[(q0 + qi) * 68 + mt + mi] = sv;
      }
    }
    __syncthreads();

#pragma unroll
    for (int j4 = 0; j4 < 4; ++j4) {
      float4 sv = *(const float4*)&SS[r * 68 + qq * 16 + j4 * 4];
      int mb = m0 + qq * 16 + j4 * 4;
      unsigned long long k0 = packkey(sv.x, mb + 0);
      INSERT_KEY(k0)
      unsigned long long k1 = packkey(sv.y, mb + 1);
      INSERT_KEY(k1)
      unsigned long long k2 = packkey(sv.z, mb + 2);
      INSERT_KEY(k2)
      unsigned long long k3 = packkey(sv.w, mb + 3);
      INSERT_KEY(k3)
    }
  }

  __syncthreads();
  unsigned long long* keys = (unsigned long long*)smem;
#pragma unroll
  for (int k = 0; k < KNN; ++k) keys[t * KNN + k] = kv[k];
  __syncthreads();
  if (t < 64) {
    for (int q2 = 1; q2 < 4; ++q2) {
      int base = (q2 * 64 + t) * KNN;
#pragma unroll 1
      for (int k = 0; k < KNN; ++k) {
        unsigned long long key = keys[base + k];
        if (key <= kv[KNN - 1]) break;
        INSERT_KEY(key)
      }
    }
    int* dst = idx + (size_t)(b * NN + n0 + t) * KNN;
#pragma unroll
    for (int k = 0; k < KNN; ++k)
      dst[k] = (NN - 1) - (int)(unsigned int)(kv[k] & 0xFFFFFFFFull);
  }
}

// ====== h(edge)·W, einsum count=128 = two chained vstepx4 iterations
// (desc blocks within each iteration), then the 16-lane reduce tree.
// Chains BIT-IDENTICAL to R11/R15; center row fv read from LDS broadcast. ======
#define EDGE_H_NP(ln, fp, fnp, w0, w1, OUTVAR)                                  \
  {                                                                             \
    _Pragma("unroll")                                                           \
    for (int dd = 0; dd < 4; ++dd) {                                            \
      int c4b = (3 - dd) * 4;                                                   \
      _Pragma("unroll")                                                         \
      for (int g = 0; g < 4; ++g) {                                             \
        int c4 = c4b + g;                                                       \
        float4 fm = *(const float4*)(fp + c4 * 4);                              \
        float4 fv = *(const float4*)(fnp + c4 * 4);                             \
        float4 wv = w0[c4];                                                     \
        float e0 = fm.x - fv.x, e1 = fm.y - fv.y;                               \
        float e2 = fm.z - fv.z, e3 = fm.w - fv.w;                               \
        int l = g * 4;                                                          \
        if (dd == 0) {                                                          \
          ln[l + 0] = mul_nf(e0, wv.x); ln[l + 1] = mul_nf(e1, wv.y);           \
          ln[l + 2] = mul_nf(e2, wv.z); ln[l + 3] = mul_nf(e3, wv.w);           \
        } else {                                                                \
          ln[l + 0] = fmaf(e0, wv.x, ln[l + 0]);                                \
          ln[l + 1] = fmaf(e1, wv.y, ln[l + 1]);                                \
          ln[l + 2] = fmaf(e2, wv.z, ln[l + 2]);                                \
          ln[l + 3] = fmaf(e3, wv.w, ln[l + 3]);                                \
        }                                                                       \
      }                                                                         \
    }                                                                           \
    _Pragma("unroll")                                                           \
    for (int dd = 0; dd < 4; ++dd) {                                            \
      int c4b = (3 - dd) * 4;                                                   \
      _Pragma("unroll")                                                         \
      for (int g = 0; g < 4; ++g) {                                             \
        int c4 = c4b + g;                                                       \
        float4 fv = *(const float4*)(fnp + c4 * 4);                             \
        float4 wv = w1[c4];                                                     \
        int l = g * 4;                                                          \
        ln[l + 0] = fmaf(fv.x, wv.x, ln[l + 0]);                                \
        ln[l + 1] = fmaf(fv.y, wv.y, ln[l + 1]);                                \
        ln[l + 2] = fmaf(fv.z, wv.z, ln[l + 2]);                                \
        ln[l + 3] = fmaf(fv.w, wv.w, ln[l + 3]);                                \
      }                                                                         \
    }                                                                           \
    float t3_[8];                                                               \
    _Pragma("unroll")                                                           \
    for (int j = 0; j < 8; ++j) t3_[j] = ln[j + 8] + ln[j];                     \
    float t6_0 = t3_[4] + t3_[0], t6_1 = t3_[5] + t3_[1];                       \
    float t6_2 = t3_[6] + t3_[2], t6_3 = t3_[7] + t3_[3];                       \
    float t8_0 = t6_0 + t6_2, t8_1 = t6_1 + t6_3;                               \
    OUTVAR = t8_0 + t8_1;                                                       \
  }

// ====== EdgeConv stats: single-edge chains; per-(n,o) running hmax/hmin
// (monotone BN+leaky commutes with extremum — bit-exact). fv from LDS
// broadcast; NO min-wave clause (R16's (256,3) spilled w0/w1 -> 11 GB
// scratch traffic). Let the allocator settle ~150-170 VGPR naturally. ======
template <int CACHE>
__global__ __launch_bounds__(256) void stats_k(const float* __restrict__ F,
                                               const float* __restrict__ W,
                                               const int* __restrict__ idx,
                                               double* __restrict__ sums,
                                               float* __restrict__ hmm) {
  __shared__ float Fn[64 * 64];
  __shared__ double rs[256], rss[256];
  int b = blockIdx.y, n0 = blockIdx.x * 64, t = threadIdx.x;
  int o = t & 63, g4 = t >> 6;
#pragma unroll
  for (int j = 0; j < 4; ++j) {
    int v = t + 256 * j;
    int row = v >> 4, c4 = (v & 15) * 4;
    *(float4*)&Fn[row * 64 + c4] =
        *(const float4*)(F + ((size_t)(b * NN + n0 + row)) * CC + c4);
  }
  float4 w0[16], w1[16];
  const float* wp = W + o * 128;
#pragma unroll
  for (int c4 = 0; c4 < 16; ++c4) {
    w0[c4] = *(const float4*)(wp + c4 * 4);
    w1[c4] = *(const float4*)(wp + 64 + c4 * 4);
  }
  __syncthreads();
  double s = 0.0, ss = 0.0;
  for (int i = 0; i < 16; ++i) {
    int n = n0 + g4 * 16 + i;
    const float* fnp = &Fn[(g4 * 16 + i) * 64];
    const int* ip = idx + ((size_t)(b * NN + n)) * KNN;
    float hmx = -3.0e38f, hmn = 3.0e38f;
#pragma unroll 1
    for (int k = 0; k < KNN; ++k) {
      const float* fp = F + ((size_t)(b * NN + ip[k])) * CC;
      float ln[16];
      float a0;
      EDGE_H_NP(ln, fp, fnp, w0, w1, a0)
      s += (double)a0;
      ss += (double)a0 * (double)a0;
      if (CACHE) {
        hmx = fmaxf(hmx, a0);
        hmn = fminf(hmn, a0);
      }
    }
    if (CACHE) {
      size_t base = ((size_t)(b * NN + n)) * CC + o;
      hmm[base] = hmx;
      hmm[(size_t)BB * NN * CC + base] = hmn;
    }
  }
  rs[t] = s; rss[t] = ss;
  __syncthreads();
  if (t < 64) {
    double a = rs[t] + rs[t + 64] + rs[t + 128] + rs[t + 192];
    double q = rss[t] + rss[t + 64] + rss[t + 128] + rss[t + 192];
    atomicAdd(&sums[o], a);
    atomicAdd(&sums[64 + o], q);
  }
}

// ====== BN finalize for edge layers: f64 stats -> f32 mean + f32 rs ======
__global__ void finalize_np(const double* __restrict__ sums, double cntinv,
                            float* __restrict__ mrs) {
  int c = threadIdx.x;  // 64
  double mean = sums[c] * cntinv;
  double var = sums[64 + c] * cntinv - mean * mean;
  mrs[c] = (float)mean;
  mrs[64 + c] = 1.0f / sqrtf((float)var + 1e-5f);
}

// ====== apply (fused extremum): y = leaky(((h*-m)*rs)*g + b), where
// h* = hmax if g>=0 else hmin. Same unfused chain as the per-k version. ======
__global__ __launch_bounds__(256) void apply_lite(const float* __restrict__ hmm,
                                                  const float* __restrict__ mrs,
                                                  const float* __restrict__ gv,
                                                  const float* __restrict__ bvv,
                                                  float* __restrict__ Fo) {
  size_t i = (size_t)blockIdx.x * 256 + threadIdx.x;
  int o = (int)(i & 63);
  float gg = gv[o];
  float h = (gg >= 0.f) ? hmm[i] : hmm[(size_t)BB * NN * CC + i];
  float d = h - mrs[o];
  d = mul_nf(d, mrs[64 + o]);
  d = mul_nf(d, gg);
  float y = d + bvv[o];
  y = y >= 0.f ? y : 0.2f * y;
  Fo[i] = y;
}

// ====== apply (recompute fallback, no-cache path) ======
__global__ __launch_bounds__(256) void apply_rec(const float* __restrict__ F,
                                                 const float* __restrict__ W,
                                                 const int* __restrict__ idx,
                                                 const float* __restrict__ mrs,
                                                 const float* __restrict__ gv,
                                                 const float* __restrict__ bvv,
                                                 float* __restrict__ Fo) {
  __shared__ float Fn[64 * 64];
  int b = blockIdx.y, n0 = blockIdx.x * 64, t = threadIdx.x;
  int o = t & 63, g4 = t >> 6;
#pragma unroll
  for (int j = 0; j < 4; ++j) {
    int v = t + 256 * j;
    int row = v >> 4, c4 = (v & 15) * 4;
    *(float4*)&Fn[row * 64 + c4] =
        *(const float4*)(F + ((size_t)(b * NN + n0 + row)) * CC + c4);
  }
  float4 w0[16], w1[16];
  const float* wp = W + o * 128;
#pragma unroll
  for (int c4 = 0; c4 < 16; ++c4) {
    w0[c4] = *(const float4*)(wp + c4 * 4);
    w1[c4] = *(const float4*)(wp + 64 + c4 * 4);
  }
  __syncthreads();
  float m32 = mrs[o], rs32 = mrs[64 + o];
  float gg = gv[o], bb = bvv[o];
  for (int i = 0; i < 16; ++i) {
    int n = n0 + g4 * 16 + i;
    const float* fnp = &Fn[(g4 * 16 + i) * 64];
    const int* ip = idx + ((size_t)(b * NN + n)) * KNN;
    float mx = -3.0e38f;
#pragma unroll 1
    for (int k = 0; k < KNN; ++k) {
      const float* fp = F + ((size_t)(b * NN + ip[k])) * CC;
      float ln[16];
      float a0;
      EDGE_H_NP(ln, fp, fnp, w0, w1, a0)
      float d0 = a0 - m32; d0 = mul_nf(d0, rs32); d0 = mul_nf(d0, gg);
      float y0 = d0 + bb;
      y0 = y0 >= 0.f ? y0 : 0.2f * y0;
      mx = fmaxf(mx, y0);
    }
    Fo[((size_t)(b * NN + n)) * CC + o] = mx;
  }
}

// ====== final stats: register-blocked GEMM, 64x64 tile (value-only) ======
template <int CACHE>
__global__ __launch_bounds__(256) void fstats_gemm(const float* __restrict__ F1,
                                                   const float* __restrict__ F2,
                                                   const float* __restrict__ F3,
                                                   const float* __restrict__ Wf,
                                                   double* __restrict__ sums,
                                                   float* __restrict__ hout) {
  __shared__ __align__(16) char smem[34816];
  float* Ft = (float*)smem;                  // [64 c][68 n]
  float* Wt = (float*)(smem + 17408);        // [64 c][68 o]
  int o0 = blockIdx.x * 64;
  int r0 = blockIdx.y * 64;  // flat row = b*NN+n
  int t = threadIdx.x;
  int to = t & 15, tn = t >> 4;
  const float* fs[3] = {F1, F2, F3};

  float acc[4][4] = {};
#pragma unroll 1
  for (int ch = 0; ch < 3; ++ch) {
    __syncthreads();
#pragma unroll
    for (int j = 0; j < 16; ++j) {
      int v = t + 256 * j;
      int oo = v >> 6, c = v & 63;
      Wt[c * 68 + oo] = Wf[(size_t)(o0 + oo) * 192 + ch * 64 + c];
    }
#pragma unroll
    for (int j = 0; j < 4; ++j) {
      int v = t + 256 * j;
      int row = v >> 4, c4 = (v & 15) * 4;
      float4 val = *(const float4*)(fs[ch] + ((size_t)(r0 + row)) * CC + c4);
      Ft[(c4 + 0) * 68 + row] = val.x;
      Ft[(c4 + 1) * 68 + row] = val.y;
      Ft[(c4 + 2) * 68 + row] = val.z;
      Ft[(c4 + 3) * 68 + row] = val.w;
    }
    __syncthreads();
#pragma unroll 8
    for (int c = 0; c < 64; ++c) {
      float4 av = *(const float4*)&Ft[c * 68 + tn * 4];
      float4 wv = *(const float4*)&Wt[c * 68 + to * 4];
      float a[4] = {av.x, av.y, av.z, av.w};
      float w[4] = {wv.x, wv.y, wv.z, wv.w};
#pragma unroll
      for (int i = 0; i < 4; ++i)
#pragma unroll
        for (int j = 0; j < 4; ++j) acc[i][j] = fmaf(a[i], w[j], acc[i][j]);
    }
  }
  if (CACHE) {
#pragma unroll
    for (int i = 0; i < 4; ++i) {
      float4 hv = {acc[i][0], acc[i][1], acc[i][2], acc[i][3]};
      *(float4*)&hout[((size_t)(r0 + tn * 4 + i)) * OUTC + o0 + to * 4] = hv;
    }
  }
  double sj[4], ssj[4];
#pragma unroll
  for (int j = 0; j < 4; ++j) {
    sj[j] = 0.0; ssj[j] = 0.0;
#pragma unroll
    for (int i = 0; i < 4; ++i) {
      sj[j] += (double)acc[i][j];
      ssj[j] += (double)acc[i][j] * (double)acc[i][j];
    }
  }
  __syncthreads();
  double* reds = (double*)smem;            // [64 o][16 tn]
  double* redss = (double*)(smem + 8192);
#pragma unroll
  for (int j = 0; j < 4; ++j) {
    reds[(to * 4 + j) * 16 + tn] = sj[j];
    redss[(to * 4 + j) * 16 + tn] = ssj[j];
  }
  __syncthreads();
  if (t < 64) {
    double s = 0.0, ss = 0.0;
#pragma unroll
    for (int u = 0; u < 16; ++u) {
      s += reds[t * 16 + u];
      ss += redss[t * 16 + u];
    }
    atomicAdd(&sums[o0 + t], s);
    atomicAdd(&sums[1024 + o0 + t], ss);
  }
}

// ====== BN finalize (final layer): f64 math -> f32 sc/sh ======
__global__ void finalize_f(const double* __restrict__ sums,
                           const float* __restrict__ g,
                           const float* __restrict__ bb, double cntinv,
                           float* __restrict__ scsh) {
  int c = blockIdx.x * 256 + threadIdx.x;  // 1024
  double mean = sums[c] * cntinv;
  double var = sums[1024 + c] * cntinv - mean * mean;
  double sc = (double)g[c] / sqrt(var + 1e-5);
  scsh[c] = (float)sc;
  scsh[1024 + c] = (float)((double)bb[c] - mean * sc);
}

// ====== final apply from h cache: normalize + partial max over n chunk ======
__global__ __launch_bounds__(256) void fapply_stream(const float* __restrict__ hin,
                                                     const float* __restrict__ scsh,
                                                     float* __restrict__ pmax) {
  int b = blockIdx.y, t = threadIdx.x;
  int o = blockIdx.x * 256 + t;
  int nbase = blockIdx.z * (NN / 8);
  float sc = scsh[o], sh = scsh[1024 + o];
  float mx = -3.0e38f;
  const float* hp = hin + ((size_t)(b * NN + nbase)) * OUTC + o;
#pragma unroll 4
  for (int n = 0; n < NN / 8; ++n) {
    float y = fmaf(sc, hp[(size_t)n * OUTC], sh);
    y = y >= 0.f ? y : 0.2f * y;
    mx = fmaxf(mx, y);
  }
  pmax[((size_t)blockIdx.z * BB + b) * OUTC + o] = mx;
}

__global__ __launch_bounds__(256) void freduce(const float* __restrict__ pmax,
                                               float* __restrict__ out) {
  int v = blockIdx.x * 256 + threadIdx.x;  // b*OUTC+o
  float mx = -3.0e38f;
#pragma unroll
  for (int ch = 0; ch < 8; ++ch) mx = fmaxf(mx, pmax[(size_t)ch * BB * OUTC + v]);
  out[v] = mx;
}

// ====== fallback final apply (no cache) ======
__global__ __launch_bounds__(256) void fapply32(const float* __restrict__ F1,
                                                const float* __restrict__ F2,
                                                const float* __restrict__ F3,
                                                const float* __restrict__ Wf,
                                                const float* __restrict__ scsh,
                                                float* __restrict__ out) {
  __shared__ float Wl[64 * 193];
  __shared__ float redm[4][64];
  int b = blockIdx.y, o0 = blockIdx.x * 64, t = threadIdx.x;
  for (int j = 0; j < 48; ++j) {
    int v = t + 256 * j;
    int oo = v / 192, c = v - oo * 192;
    Wl[oo * 193 + c] = Wf[(size_t)(o0 + oo) * 192 + c];
  }
  __syncthreads();
  int o = t & 63, g = t >> 6;
  float sc = scsh[o0 + o], sh = scsh[1024 + o0 + o];
  const float* fs[3] = {F1, F2, F3};
  float mx = -3.0e38f;
  for (int n0 = 0; n0 < NN; n0 += 16) {
    int n = n0 + g * 4;
    float h[4] = {0.f, 0.f, 0.f, 0.f};
#pragma unroll
    for (int part = 0; part < 3; ++part) {
      const float* src = fs[part] + ((size_t)(b * NN + n)) * CC;
      const float* wp = &Wl[o * 193 + part * 64];
#pragma unroll 4
      for (int c4 = 0; c4 < 16; ++c4) {
        float4 w4 = {wp[c4 * 4], wp[c4 * 4 + 1], wp[c4 * 4 + 2], wp[c4 * 4 + 3]};
#pragma unroll
        for (int i = 0; i < 4; ++i) {
          float4 v = *(const float4*)(src + (size_t)i * CC + c4 * 4);
          h[i] = fmaf(w4.x, v.x, h[i]);
          h[i] = fmaf(w4.y, v.y, h[i]);
          h[i] = fmaf(w4.z, v.z, h[i]);
          h[i] = fmaf(w4.w, v.w, h[i]);
        }
      }
    }
#pragma unroll
    for (int i = 0; i < 4; ++i) {
      float y = fmaf(sc, h[i], sh);
      y = y >= 0.f ? y : 0.2f * y;
      mx = fmaxf(mx, y);
    }
  }
  redm[g][o] = mx;
  __syncthreads();
  if (t < 64) {
    float m = fmaxf(fmaxf(redm[0][o], redm[1][o]), fmaxf(redm[2][o], redm[3][o]));
    out[(size_t)b * OUTC + o0 + o] = m;
  }
}

extern "C" void kernel_launch(void* const* d_in, const int* in_sizes, int n_in,
                              void* d_out, int out_size, void* d_ws, size_t ws_size,
                              hipStream_t stream) {
  (void)in_sizes; (void)n_in; (void)out_size;
  const float* x  = (const float*)d_in[0];
  const float* W1 = (const float*)d_in[1];
  const float* g1 = (const float*)d_in[2];
  const float* b1 = (const float*)d_in[3];
  const float* W2 = (const float*)d_in[4];
  const float* g2 = (const float*)d_in[5];
  const float* b2 = (const float*)d_in[6];
  const float* W3 = (const float*)d_in[7];
  const float* g3 = (const float*)d_in[8];
  const float* b3 = (const float*)d_in[9];
  const float* Wf = (const float*)d_in[10];
  const float* gf = (const float*)d_in[11];
  const float* bf = (const float*)d_in[12];
  float* out = (float*)d_out;

  char* wsb = (char*)d_ws;
  float* F1f    = (float*)(wsb + 0);           // 8 MB
  float* F2f    = (float*)(wsb + 8388608);     // 8 MB
  float* F3f    = (float*)(wsb + 16777216);    // 8 MB
  float* xxf    = (float*)(wsb + 25165824);    // 128 KB
  int* idx      = (int*)(wsb + 25296896);      // 2.62 MB
  double* sumsd = (double*)(wsb + 27918336);   // 128 doubles
  double* fsums = (double*)(wsb + 27920384);   // 2048 doubles
  float* fscsh  = (float*)(wsb + 27936768);    // 2048 floats
  float* mrs    = (float*)(wsb + 27944960);    // 128 floats
  float* pmax   = (float*)(wsb + 27945984);    // 512 KB
  float* hmmb   = (float*)(wsb + 29360128);    // 16.78 MB (hmax+hmin planes)
  float* hbuf   = (float*)(wsb + 29360128 + 16777216);  // 134.2 MB final h
  const bool cache = ws_size >= (size_t)29360128 + (size_t)BB * NN * KNN * 64 * 4;

  const float* Fin[3] = {x, F1f, F2f};
  float* Fout[3] = {F1f, F2f, F3f};
  const float* Ws[3] = {W1, W2, W3};
  const float* gs[3] = {g1, g2, g3};
  const float* bs[3] = {b1, b2, b3};

  for (int L = 0; L < 3; ++L) {
    xx32_kernel<<<dim3(BB * NN / 256), 256, 0, stream>>>(Fin[L], xxf);
    knn_fast<<<dim3(NN / 64, BB), 256, 0, stream>>>(Fin[L], xxf, idx);
    hipMemsetAsync(sumsd, 0, 128 * sizeof(double), stream);
    if (cache) {
      stats_k<1><<<dim3(NN / 64, BB), 256, 0, stream>>>(Fin[L], Ws[L], idx, sumsd, hmmb);
      finalize_np<<<1, 64, 0, stream>>>(sumsd, 1.0 / (double)(BB * NN * KNN), mrs);
      apply_lite<<<dim3(BB * NN * CC / 256), 256, 0, stream>>>(hmmb, mrs, gs[L], bs[L],
                                                               Fout[L]);
    } else {
      stats_k<0><<<dim3(NN / 64, BB), 256, 0, stream>>>(Fin[L], Ws[L], idx, sumsd, nullptr);
      finalize_np<<<1, 64, 0, stream>>>(sumsd, 1.0 / (double)(BB * NN * KNN), mrs);
      apply_rec<<<dim3(NN / 64, BB), 256, 0, stream>>>(Fin[L], Ws[L], idx, mrs,
                                                       gs[L], bs[L], Fout[L]);
    }
  }
  hipMemsetAsync(fsums, 0, 2048 * sizeof(double), stream);
  if (cache) {
    fstats_gemm<1><<<dim3(OUTC / 64, BB * NN / 64), 256, 0, stream>>>(F1f, F2f, F3f,
                                                                      Wf, fsums, hbuf);
    finalize_f<<<4, 256, 0, stream>>>(fsums, gf, bf, 1.0 / (double)(BB * NN), fscsh);
    fapply_stream<<<dim3(OUTC / 256, BB, 8), 256, 0, stream>>>(hbuf, fscsh, pmax);
    freduce<<<dim3(BB * OUTC / 256), 256, 0, stream>>>(pmax, out);
  } else {
    fstats_gemm<0><<<dim3(OUTC / 64, BB * NN / 64), 256, 0, stream>>>(F1f, F2f, F3f,
                                                                      Wf, fsums, nullptr);
    finalize_f<<<4, 256, 0, stream>>>(fsums, gf, bf, 1.0 / (double)(BB * NN), fscsh);
    fapply32<<<dim3(OUTC / 64, BB), 256, 0, stream>>>(F1f, F2f, F3f, Wf, fscsh, out);
  }
}

// Round 18
// 2535.486 us; speedup vs baseline: 6.0696x; 1.4743x over previous
//
#include <hip/hip_runtime.h>

#define BB 16
#define NN 2048
#define CC 64
#define KNN 20
#define OUTC 1024

// non-fusable f32 multiply: inline-asm v_mul_f32 blocks -ffp-contract=fast
// from fusing a rounded product into a following add (numpy materializes
// rounded products at ufunc boundaries).
__device__ __forceinline__ float mul_nf(float a, float b) {
  float r;
  asm("v_mul_f32 %0, %1, %2" : "=v"(r) : "v"(a), "v"(b));
  return r;
}

// ====== xx: np.sum(f*f, -1) via DISPATCHED FLOAT_pairwise_sum, AVX512 npyv:
// n=64 -> r0..r3 = 16-lane loads of the rounded squares; vectorwise
// (r0+r1)+(r2+r3); then _mm512_reduce_add_ps tree. ======
__global__ __launch_bounds__(256) void xx32_kernel(const float* __restrict__ F,
                                                   float* __restrict__ xxf) {
  int p = blockIdx.x * 256 + threadIdx.x;
  const float* f = F + (size_t)p * CC;
  float t[64];
#pragma unroll
  for (int c = 0; c < 64; ++c) t[c] = mul_nf(f[c], f[c]);
  float v[16];
#pragma unroll
  for (int l = 0; l < 16; ++l)
    v[l] = (t[l] + t[16 + l]) + (t[32 + l] + t[48 + l]);
  float t3[8];
#pragma unroll
  for (int j = 0; j < 8; ++j) t3[j] = v[j] + v[j + 8];
  float t6[4];
#pragma unroll
  for (int k = 0; k < 4; ++k) t6[k] = t3[k] + t3[k + 4];
  xxf[p] = (t6[0] + t6[2]) + (t6[1] + t6[3]);
}

// ====== packed top-k key: monotone f32 score (hi) | inverted index (lo).
// Ties -> SMALLER index wins. ======
__device__ __forceinline__ unsigned long long packkey(float s, int m) {
  unsigned int u = __float_as_uint(s);
  u ^= (u >> 31) ? 0xFFFFFFFFu : 0x80000000u;
  return ((unsigned long long)u << 32) | (unsigned int)(NN - 1 - m);
}

#define INSERT_KEY(key)                                   \
  if ((key) > kv[KNN - 1]) {                              \
    _Pragma("unroll")                                     \
    for (int jj = KNN - 1; jj >= 1; --jj) {               \
      if ((key) > kv[jj - 1]) kv[jj] = kv[jj - 1];        \
      else if ((key) > kv[jj]) kv[jj] = (key);            \
    }                                                     \
    if ((key) > kv[0]) kv[0] = (key);                     \
  }

// ====== kNN gram: numpy c_einsum SOP, AVX512 npyv, count=64 = one vstepx4
// iteration of the chained muladd (desc blocks ab3..ab0), then reduce tree. ======
__global__ __launch_bounds__(256) void knn_fast(const float* __restrict__ F,
                                                const float* __restrict__ xxf,
                                                int* __restrict__ idx) {
  __shared__ __align__(16) char smem[52736];
  float* SQ = (float*)smem;                   // [64 row][68] row-major
  float* SP = (float*)(smem + 17408);         // [64 row][68]
  float* SS = (float*)(smem + 34816);         // [64 row][68]
  float* xq = (float*)(smem + 52224);
  float* xp = (float*)(smem + 52480);

  int b = blockIdx.y, n0 = blockIdx.x * 64, t = threadIdx.x;
  const float* fb = F + (size_t)b * NN * CC;

#pragma unroll
  for (int j = 0; j < 4; ++j) {
    int v = t + 256 * j;
    int row = v >> 4, c4 = (v & 15) * 4;
    *(float4*)&SQ[row * 68 + c4] = *(const float4*)(fb + (size_t)(n0 + row) * CC + c4);
  }
  if (t < 64) xq[t] = xxf[b * NN + n0 + t];

  unsigned long long kv[KNN];
#pragma unroll
  for (int k = 0; k < KNN; ++k) kv[k] = 0ull;

  int tx = t & 7, ty = t >> 3;   // gram mapping: 2 queries x 2 m per thread
  int q0 = ty * 2;
  int r = t & 63, qq = t >> 6;   // insertion mapping

  for (int m0 = 0; m0 < NN; m0 += 64) {
    __syncthreads();
#pragma unroll
    for (int j = 0; j < 4; ++j) {
      int v = t + 256 * j;
      int row = v >> 4, c4 = (v & 15) * 4;
      *(float4*)&SP[row * 68 + c4] = *(const float4*)(fb + (size_t)(m0 + row) * CC + c4);
    }
    if (t < 64) xp[t] = xxf[b * NN + m0 + t];
    __syncthreads();

#pragma unroll 1
    for (int p = 0; p < 4; ++p) {
      int mt = p * 16 + tx * 2;
      float ln[4][16];  // [qi*2+mi][lane]
#pragma unroll
      for (int dd = 0; dd < 4; ++dd) {
        int cc = (3 - dd) * 16;  // descending 16-blocks: numpy ab3..ab0 chain
#pragma unroll
        for (int g = 0; g < 4; ++g) {
          float4 a0 = *(const float4*)&SQ[q0 * 68 + cc + g * 4];
          float4 a1 = *(const float4*)&SQ[(q0 + 1) * 68 + cc + g * 4];
          float4 c0 = *(const float4*)&SP[mt * 68 + cc + g * 4];
          float4 c1 = *(const float4*)&SP[(mt + 1) * 68 + cc + g * 4];
          float av0[4] = {a0.x, a0.y, a0.z, a0.w};
          float av1[4] = {a1.x, a1.y, a1.z, a1.w};
          float bv0[4] = {c0.x, c0.y, c0.z, c0.w};
          float bv1[4] = {c1.x, c1.y, c1.z, c1.w};
#pragma unroll
          for (int e = 0; e < 4; ++e) {
            int l = g * 4 + e;
            if (dd == 0) {
              ln[0][l] = mul_nf(av0[e], bv0[e]);
              ln[1][l] = mul_nf(av0[e], bv1[e]);
              ln[2][l] = mul_nf(av1[e], bv0[e]);
              ln[3][l] = mul_nf(av1[e], bv1[e]);
            } else {
              ln[0][l] = fmaf(av0[e], bv0[e], ln[0][l]);
              ln[1][l] = fmaf(av0[e], bv1[e], ln[1][l]);
              ln[2][l] = fmaf(av1[e], bv0[e], ln[2][l]);
              ln[3][l] = fmaf(av1[e], bv1[e], ln[3][l]);
            }
          }
        }
      }
      // _mm512_reduce_add_ps tree
#pragma unroll
      for (int pp = 0; pp < 4; ++pp) {
        float t3[8];
#pragma unroll
        for (int j = 0; j < 8; ++j) t3[j] = ln[pp][j + 8] + ln[pp][j];
        float t6_0 = t3[4] + t3[0], t6_1 = t3[5] + t3[1];
        float t6_2 = t3[6] + t3[2], t6_3 = t3[7] + t3[3];
        float t8_0 = t6_0 + t6_2, t8_1 = t6_1 + t6_3;
        float s = t8_0 + t8_1;
        int qi = pp >> 1, mi = pp & 1;
        float sv = (2.0f * s - xq[q0 + qi]) - xp[mt + mi];
        SS[(q0 + qi) * 68 + mt + mi] = sv;
      }
    }
    __syncthreads();

#pragma unroll
    for (int j4 = 0; j4 < 4; ++j4) {
      float4 sv = *(const float4*)&SS[r * 68 + qq * 16 + j4 * 4];
      int mb = m0 + qq * 16 + j4 * 4;
      unsigned long long k0 = packkey(sv.x, mb + 0);
      INSERT_KEY(k0)
      unsigned long long k1 = packkey(sv.y, mb + 1);
      INSERT_KEY(k1)
      unsigned long long k2 = packkey(sv.z, mb + 2);
      INSERT_KEY(k2)
      unsigned long long k3 = packkey(sv.w, mb + 3);
      INSERT_KEY(k3)
    }
  }

  __syncthreads();
  unsigned long long* keys = (unsigned long long*)smem;
#pragma unroll
  for (int k = 0; k < KNN; ++k) keys[t * KNN + k] = kv[k];
  __syncthreads();
  if (t < 64) {
    for (int q2 = 1; q2 < 4; ++q2) {
      int base = (q2 * 64 + t) * KNN;
#pragma unroll 1
      for (int k = 0; k < KNN; ++k) {
        unsigned long long key = keys[base + k];
        if (key <= kv[KNN - 1]) break;
        INSERT_KEY(key)
      }
    }
    int* dst = idx + (size_t)(b * NN + n0 + t) * KNN;
#pragma unroll
    for (int k = 0; k < KNN; ++k)
      dst[k] = (NN - 1) - (int)(unsigned int)(kv[k] & 0xFFFFFFFFull);
  }
}

// ====== h(edge)·W, einsum count=128 = two chained vstepx4 iterations
// (desc blocks within each iteration), then the 16-lane reduce tree.
// BIT-IDENTICAL chains to R11/R15 (register fn). ======
#define EDGE_H_NP(ln, fp, fn, w0, w1, OUTVAR)                                   \
  {                                                                             \
    _Pragma("unroll")                                                           \
    for (int dd = 0; dd < 4; ++dd) {                                            \
      int c4b = (3 - dd) * 4;                                                   \
      _Pragma("unroll")                                                         \
      for (int g = 0; g < 4; ++g) {                                             \
        int c4 = c4b + g;                                                       \
        float4 fm = *(const float4*)(fp + c4 * 4);                              \
        float4 fv = fn[c4];                                                     \
        float4 wv = w0[c4];                                                     \
        float e0 = fm.x - fv.x, e1 = fm.y - fv.y;                               \
        float e2 = fm.z - fv.z, e3 = fm.w - fv.w;                               \
        int l = g * 4;                                                          \
        if (dd == 0) {                                                          \
          ln[l + 0] = mul_nf(e0, wv.x); ln[l + 1] = mul_nf(e1, wv.y);           \
          ln[l + 2] = mul_nf(e2, wv.z); ln[l + 3] = mul_nf(e3, wv.w);           \
        } else {                                                                \
          ln[l + 0] = fmaf(e0, wv.x, ln[l + 0]);                                \
          ln[l + 1] = fmaf(e1, wv.y, ln[l + 1]);                                \
          ln[l + 2] = fmaf(e2, wv.z, ln[l + 2]);                                \
          ln[l + 3] = fmaf(e3, wv.w, ln[l + 3]);                                \
        }                                                                       \
      }                                                                         \
    }                                                                           \
    _Pragma("unroll")                                                           \
    for (int dd = 0; dd < 4; ++dd) {                                            \
      int c4b = (3 - dd) * 4;                                                   \
      _Pragma("unroll")                                                         \
      for (int g = 0; g < 4; ++g) {                                             \
        int c4 = c4b + g;                                                       \
        float4 fv = fn[c4];                                                     \
        float4 wv = w1[c4];                                                     \
        int l = g * 4;                                                          \
        ln[l + 0] = fmaf(fv.x, wv.x, ln[l + 0]);                                \
        ln[l + 1] = fmaf(fv.y, wv.y, ln[l + 1]);                                \
        ln[l + 2] = fmaf(fv.z, wv.z, ln[l + 2]);                                \
        ln[l + 3] = fmaf(fv.w, wv.w, ln[l + 3]);                                \
      }                                                                         \
    }                                                                           \
    float t3_[8];                                                               \
    _Pragma("unroll")                                                           \
    for (int j = 0; j < 8; ++j) t3_[j] = ln[j + 8] + ln[j];                     \
    float t6_0 = t3_[4] + t3_[0], t6_1 = t3_[5] + t3_[1];                       \
    float t6_2 = t3_[6] + t3_[2], t6_3 = t3_[7] + t3_[3];                       \
    float t8_0 = t6_0 + t6_2, t8_1 = t6_1 + t6_3;                               \
    OUTVAR = t8_0 + t8_1;                                                       \
  }

// ====== EdgeConv stats: R15 structure (register fn, hmax/hmin fusion) +
// readfirstlane on the neighbor index: the row pointer becomes provably
// wave-uniform -> compiler emits s_load (scalar, lgkmcnt, constant cache),
// freeing VGPRs/VALU slots and letting loads hoist over prior-edge math. ======
template <int CACHE>
__global__ __launch_bounds__(256) void stats_k(const float* __restrict__ F,
                                               const float* __restrict__ W,
                                               const int* __restrict__ idx,
                                               double* __restrict__ sums,
                                               float* __restrict__ hmm) {
  __shared__ float Fn[64 * 64];
  __shared__ double rs[256], rss[256];
  int b = blockIdx.y, n0 = blockIdx.x * 64, t = threadIdx.x;
  int o = t & 63, g4 = t >> 6;
#pragma unroll
  for (int j = 0; j < 4; ++j) {
    int v = t + 256 * j;
    int row = v >> 4, c4 = (v & 15) * 4;
    *(float4*)&Fn[row * 64 + c4] =
        *(const float4*)(F + ((size_t)(b * NN + n0 + row)) * CC + c4);
  }
  float4 w0[16], w1[16];
  const float* wp = W + o * 128;
#pragma unroll
  for (int c4 = 0; c4 < 16; ++c4) {
    w0[c4] = *(const float4*)(wp + c4 * 4);
    w1[c4] = *(const float4*)(wp + 64 + c4 * 4);
  }
  __syncthreads();
  double s = 0.0, ss = 0.0;
  for (int i = 0; i < 16; ++i) {
    int n = n0 + g4 * 16 + i;
    float4 fn[16];
#pragma unroll
    for (int c4 = 0; c4 < 16; ++c4) fn[c4] = *(float4*)&Fn[(g4 * 16 + i) * 64 + c4 * 4];
    const int* ip = idx + ((size_t)(b * NN + n)) * KNN;
    float hmx = -3.0e38f, hmn = 3.0e38f;
#pragma unroll 1
    for (int k = 0; k < KNN; ++k) {
      int m = __builtin_amdgcn_readfirstlane(ip[k]);  // wave-uniform neighbor
      const float* fp = F + ((size_t)(b * NN + m)) * CC;
      float ln[16];
      float a0;
      EDGE_H_NP(ln, fp, fn, w0, w1, a0)
      s += (double)a0;
      ss += (double)a0 * (double)a0;
      if (CACHE) {
        hmx = fmaxf(hmx, a0);
        hmn = fminf(hmn, a0);
      }
    }
    if (CACHE) {
      size_t base = ((size_t)(b * NN + n)) * CC + o;
      hmm[base] = hmx;
      hmm[(size_t)BB * NN * CC + base] = hmn;
    }
  }
  rs[t] = s; rss[t] = ss;
  __syncthreads();
  if (t < 64) {
    double a = rs[t] + rs[t + 64] + rs[t + 128] + rs[t + 192];
    double q = rss[t] + rss[t + 64] + rss[t + 128] + rss[t + 192];
    atomicAdd(&sums[o], a);
    atomicAdd(&sums[64 + o], q);
  }
}

// ====== BN finalize for edge layers: f64 stats -> f32 mean + f32 rs ======
__global__ void finalize_np(const double* __restrict__ sums, double cntinv,
                            float* __restrict__ mrs) {
  int c = threadIdx.x;  // 64
  double mean = sums[c] * cntinv;
  double var = sums[64 + c] * cntinv - mean * mean;
  mrs[c] = (float)mean;
  mrs[64 + c] = 1.0f / sqrtf((float)var + 1e-5f);
}

// ====== apply (fused extremum): y = leaky(((h*-m)*rs)*g + b), where
// h* = hmax if g>=0 else hmin. Same unfused chain as the per-k version. ======
__global__ __launch_bounds__(256) void apply_lite(const float* __restrict__ hmm,
                                                  const float* __restrict__ mrs,
                                                  const float* __restrict__ gv,
                                                  const float* __restrict__ bvv,
                                                  float* __restrict__ Fo) {
  size_t i = (size_t)blockIdx.x * 256 + threadIdx.x;
  int o = (int)(i & 63);
  float gg = gv[o];
  float h = (gg >= 0.f) ? hmm[i] : hmm[(size_t)BB * NN * CC + i];
  float d = h - mrs[o];
  d = mul_nf(d, mrs[64 + o]);
  d = mul_nf(d, gg);
  float y = d + bvv[o];
  y = y >= 0.f ? y : 0.2f * y;
  Fo[i] = y;
}

// ====== apply (recompute fallback, no-cache path) ======
__global__ __launch_bounds__(256) void apply_rec(const float* __restrict__ F,
                                                 const float* __restrict__ W,
                                                 const int* __restrict__ idx,
                                                 const float* __restrict__ mrs,
                                                 const float* __restrict__ gv,
                                                 const float* __restrict__ bvv,
                                                 float* __restrict__ Fo) {
  __shared__ float Fn[64 * 64];
  int b = blockIdx.y, n0 = blockIdx.x * 64, t = threadIdx.x;
  int o = t & 63, g4 = t >> 6;
#pragma unroll
  for (int j = 0; j < 4; ++j) {
    int v = t + 256 * j;
    int row = v >> 4, c4 = (v & 15) * 4;
    *(float4*)&Fn[row * 64 + c4] =
        *(const float4*)(F + ((size_t)(b * NN + n0 + row)) * CC + c4);
  }
  float4 w0[16], w1[16];
  const float* wp = W + o * 128;
#pragma unroll
  for (int c4 = 0; c4 < 16; ++c4) {
    w0[c4] = *(const float4*)(wp + c4 * 4);
    w1[c4] = *(const float4*)(wp + 64 + c4 * 4);
  }
  __syncthreads();
  float m32 = mrs[o], rs32 = mrs[64 + o];
  float gg = gv[o], bb = bvv[o];
  for (int i = 0; i < 16; ++i) {
    int n = n0 + g4 * 16 + i;
    float4 fn[16];
#pragma unroll
    for (int c4 = 0; c4 < 16; ++c4) fn[c4] = *(float4*)&Fn[(g4 * 16 + i) * 64 + c4 * 4];
    const int* ip = idx + ((size_t)(b * NN + n)) * KNN;
    float mx = -3.0e38f;
#pragma unroll 1
    for (int k = 0; k < KNN; ++k) {
      int m = __builtin_amdgcn_readfirstlane(ip[k]);
      const float* fp = F + ((size_t)(b * NN + m)) * CC;
      float ln[16];
      float a0;
      EDGE_H_NP(ln, fp, fn, w0, w1, a0)
      float d0 = a0 - m32; d0 = mul_nf(d0, rs32); d0 = mul_nf(d0, gg);
      float y0 = d0 + bb;
      y0 = y0 >= 0.f ? y0 : 0.2f * y0;
      mx = fmaxf(mx, y0);
    }
    Fo[((size_t)(b * NN + n)) * CC + o] = mx;
  }
}

// ====== final stats: register-blocked GEMM, 64x64 tile (value-only) ======
template <int CACHE>
__global__ __launch_bounds__(256) void fstats_gemm(const float* __restrict__ F1,
                                                   const float* __restrict__ F2,
                                                   const float* __restrict__ F3,
                                                   const float* __restrict__ Wf,
                                                   double* __restrict__ sums,
                                                   float* __restrict__ hout) {
  __shared__ __align__(16) char smem[34816];
  float* Ft = (float*)smem;                  // [64 c][68 n]
  float* Wt = (float*)(smem + 17408);        // [64 c][68 o]
  int o0 = blockIdx.x * 64;
  int r0 = blockIdx.y * 64;  // flat row = b*NN+n
  int t = threadIdx.x;
  int to = t & 15, tn = t >> 4;
  const float* fs[3] = {F1, F2, F3};

  float acc[4][4] = {};
#pragma unroll 1
  for (int ch = 0; ch < 3; ++ch) {
    __syncthreads();
#pragma unroll
    for (int j = 0; j < 16; ++j) {
      int v = t + 256 * j;
      int oo = v >> 6, c = v & 63;
      Wt[c * 68 + oo] = Wf[(size_t)(o0 + oo) * 192 + ch * 64 + c];
    }
#pragma unroll
    for (int j = 0; j < 4; ++j) {
      int v = t + 256 * j;
      int row = v >> 4, c4 = (v & 15) * 4;
      float4 val = *(const float4*)(fs[ch] + ((size_t)(r0 + row)) * CC + c4);
      Ft[(c4 + 0) * 68 + row] = val.x;
      Ft[(c4 + 1) * 68 + row] = val.y;
      Ft[(c4 + 2) * 68 + row] = val.z;
      Ft[(c4 + 3) * 68 + row] = val.w;
    }
    __syncthreads();
#pragma unroll 8
    for (int c = 0; c < 64; ++c) {
      float4 av = *(const float4*)&Ft[c * 68 + tn * 4];
      float4 wv = *(const float4*)&Wt[c * 68 + to * 4];
      float a[4] = {av.x, av.y, av.z, av.w};
      float w[4] = {wv.x, wv.y, wv.z, wv.w};
#pragma unroll
      for (int i = 0; i < 4; ++i)
#pragma unroll
        for (int j = 0; j < 4; ++j) acc[i][j] = fmaf(a[i], w[j], acc[i][j]);
    }
  }
  if (CACHE) {
#pragma unroll
    for (int i = 0; i < 4; ++i) {
      float4 hv = {acc[i][0], acc[i][1], acc[i][2], acc[i][3]};
      *(float4*)&hout[((size_t)(r0 + tn * 4 + i)) * OUTC + o0 + to * 4] = hv;
    }
  }
  double sj[4], ssj[4];
#pragma unroll
  for (int j = 0; j < 4; ++j) {
    sj[j] = 0.0; ssj[j] = 0.0;
#pragma unroll
    for (int i = 0; i < 4; ++i) {
      sj[j] += (double)acc[i][j];
      ssj[j] += (double)acc[i][j] * (double)acc[i][j];
    }
  }
  __syncthreads();
  double* reds = (double*)smem;            // [64 o][16 tn]
  double* redss = (double*)(smem + 8192);
#pragma unroll
  for (int j = 0; j < 4; ++j) {
    reds[(to * 4 + j) * 16 + tn] = sj[j];
    redss[(to * 4 + j) * 16 + tn] = ssj[j];
  }
  __syncthreads();
  if (t < 64) {
    double s = 0.0, ss = 0.0;
#pragma unroll
    for (int u = 0; u < 16; ++u) {
      s += reds[t * 16 + u];
      ss += redss[t * 16 + u];
    }
    atomicAdd(&sums[o0 + t], s);
    atomicAdd(&sums[1024 + o0 + t], ss);
  }
}

// ====== BN finalize (final layer): f64 math -> f32 sc/sh ======
__global__ void finalize_f(const double* __restrict__ sums,
                           const float* __restrict__ g,
                           const float* __restrict__ bb, double cntinv,
                           float* __restrict__ scsh) {
  int c = blockIdx.x * 256 + threadIdx.x;  // 1024
  double mean = sums[c] * cntinv;
  double var = sums[1024 + c] * cntinv - mean * mean;
  double sc = (double)g[c] / sqrt(var + 1e-5);
  scsh[c] = (float)sc;
  scsh[1024 + c] = (float)((double)bb[c] - mean * sc);
}

// ====== final apply from h cache: normalize + partial max over n chunk ======
__global__ __launch_bounds__(256) void fapply_stream(const float* __restrict__ hin,
                                                     const float* __restrict__ scsh,
                                                     float* __restrict__ pmax) {
  int b = blockIdx.y, t = threadIdx.x;
  int o = blockIdx.x * 256 + t;
  int nbase = blockIdx.z * (NN / 8);
  float sc = scsh[o], sh = scsh[1024 + o];
  float mx = -3.0e38f;
  const float* hp = hin + ((size_t)(b * NN + nbase)) * OUTC + o;
#pragma unroll 4
  for (int n = 0; n < NN / 8; ++n) {
    float y = fmaf(sc, hp[(size_t)n * OUTC], sh);
    y = y >= 0.f ? y : 0.2f * y;
    mx = fmaxf(mx, y);
  }
  pmax[((size_t)blockIdx.z * BB + b) * OUTC + o] = mx;
}

__global__ __launch_bounds__(256) void freduce(const float* __restrict__ pmax,
                                               float* __restrict__ out) {
  int v = blockIdx.x * 256 + threadIdx.x;  // b*OUTC+o
  float mx = -3.0e38f;
#pragma unroll
  for (int ch = 0; ch < 8; ++ch) mx = fmaxf(mx, pmax[(size_t)ch * BB * OUTC + v]);
  out[v] = mx;
}

// ====== fallback final apply (no cache) ======
__global__ __launch_bounds__(256) void fapply32(const float* __restrict__ F1,
                                                const float* __restrict__ F2,
                                                const float* __restrict__ F3,
                                                const float* __restrict__ Wf,
                                                const float* __restrict__ scsh,
                                                float* __restrict__ out) {
  __shared__ float Wl[64 * 193];
  __shared__ float redm[4][64];
  int b = blockIdx.y, o0 = blockIdx.x * 64, t = threadIdx.x;
  for (int j = 0; j < 48; ++j) {
    int v = t + 256 * j;
    int oo = v / 192, c = v - oo * 192;
    Wl[oo * 193 + c] = Wf[(size_t)(o0 + oo) * 192 + c];
  }
  __syncthreads();
  int o = t & 63, g = t >> 6;
  float sc = scsh[o0 + o], sh = scsh[1024 + o0 + o];
  const float* fs[3] = {F1, F2, F3};
  float mx = -3.0e38f;
  for (int n0 = 0; n0 < NN; n0 += 16) {
    int n = n0 + g * 4;
    float h[4] = {0.f, 0.f, 0.f, 0.f};
#pragma unroll
    for (int part = 0; part < 3; ++part) {
      const float* src = fs[part] + ((size_t)(b * NN + n)) * CC;
      const float* wp = &Wl[o * 193 + part * 64];
#pragma unroll 4
      for (int c4 = 0; c4 < 16; ++c4) {
        float4 w4 = {wp[c4 * 4], wp[c4 * 4 + 1], wp[c4 * 4 + 2], wp[c4 * 4 + 3]};
#pragma unroll
        for (int i = 0; i < 4; ++i) {
          float4 v = *(const float4*)(src + (size_t)i * CC + c4 * 4);
          h[i] = fmaf(w4.x, v.x, h[i]);
          h[i] = fmaf(w4.y, v.y, h[i]);
          h[i] = fmaf(w4.z, v.z, h[i]);
          h[i] = fmaf(w4.w, v.w, h[i]);
        }
      }
    }
#pragma unroll
    for (int i = 0; i < 4; ++i) {
      float y = fmaf(sc, h[i], sh);
      y = y >= 0.f ? y : 0.2f * y;
      mx = fmaxf(mx, y);
    }
  }
  redm[g][o] = mx;
  __syncthreads();
  if (t < 64) {
    float m = fmaxf(fmaxf(redm[0][o], redm[1][o]), fmaxf(redm[2][o], redm[3][o]));
    out[(size_t)b * OUTC + o0 + o] = m;
  }
}

extern "C" void kernel_launch(void* const* d_in, const int* in_sizes, int n_in,
                              void* d_out, int out_size, void* d_ws, size_t ws_size,
                              hipStream_t stream) {
  (void)in_sizes; (void)n_in; (void)out_size;
  const float* x  = (const float*)d_in[0];
  const float* W1 = (const float*)d_in[1];
  const float* g1 = (const float*)d_in[2];
  const float* b1 = (const float*)d_in[3];
  const float* W2 = (const float*)d_in[4];
  const float* g2 = (const float*)d_in[5];
  const float* b2 = (const float*)d_in[6];
  const float* W3 = (const float*)d_in[7];
  const float* g3 = (const float*)d_in[8];
  const float* b3 = (const float*)d_in[9];
  const float* Wf = (const float*)d_in[10];
  const float* gf = (const float*)d_in[11];
  const float* bf = (const float*)d_in[12];
  float* out = (float*)d_out;

  char* wsb = (char*)d_ws;
  float* F1f    = (float*)(wsb + 0);           // 8 MB
  float* F2f    = (float*)(wsb + 8388608);     // 8 MB
  float* F3f    = (float*)(wsb + 16777216);    // 8 MB
  float* xxf    = (float*)(wsb + 25165824);    // 128 KB
  int* idx      = (int*)(wsb + 25296896);      // 2.62 MB
  double* sumsd = (double*)(wsb + 27918336);   // 128 doubles
  double* fsums = (double*)(wsb + 27920384);   // 2048 doubles
  float* fscsh  = (float*)(wsb + 27936768);    // 2048 floats
  float* mrs    = (float*)(wsb + 27944960);    // 128 floats
  float* pmax   = (float*)(wsb + 27945984);    // 512 KB
  float* hmmb   = (float*)(wsb + 29360128);    // 16.78 MB (hmax+hmin planes)
  float* hbuf   = (float*)(wsb + 29360128 + 16777216);  // 134.2 MB final h
  const bool cache = ws_size >= (size_t)29360128 + (size_t)BB * NN * KNN * 64 * 4;

  const float* Fin[3] = {x, F1f, F2f};
  float* Fout[3] = {F1f, F2f, F3f};
  const float* Ws[3] = {W1, W2, W3};
  const float* gs[3] = {g1, g2, g3};
  const float* bs[3] = {b1, b2, b3};

  for (int L = 0; L < 3; ++L) {
    xx32_kernel<<<dim3(BB * NN / 256), 256, 0, stream>>>(Fin[L], xxf);
    knn_fast<<<dim3(NN / 64, BB), 256, 0, stream>>>(Fin[L], xxf, idx);
    hipMemsetAsync(sumsd, 0, 128 * sizeof(double), stream);
    if (cache) {
      stats_k<1><<<dim3(NN / 64, BB), 256, 0, stream>>>(Fin[L], Ws[L], idx, sumsd, hmmb);
      finalize_np<<<1, 64, 0, stream>>>(sumsd, 1.0 / (double)(BB * NN * KNN), mrs);
      apply_lite<<<dim3(BB * NN * CC / 256), 256, 0, stream>>>(hmmb, mrs, gs[L], bs[L],
                                                               Fout[L]);
    } else {
      stats_k<0><<<dim3(NN / 64, BB), 256, 0, stream>>>(Fin[L], Ws[L], idx, sumsd, nullptr);
      finalize_np<<<1, 64, 0, stream>>>(sumsd, 1.0 / (double)(BB * NN * KNN), mrs);
      apply_rec<<<dim3(NN / 64, BB), 256, 0, stream>>>(Fin[L], Ws[L], idx, mrs,
                                                       gs[L], bs[L], Fout[L]);
    }
  }
  hipMemsetAsync(fsums, 0, 2048 * sizeof(double), stream);
  if (cache) {
    fstats_gemm<1><<<dim3(OUTC / 64, BB * NN / 64), 256, 0, stream>>>(F1f, F2f, F3f,
                                                                      Wf, fsums, hbuf);
    finalize_f<<<4, 256, 0, stream>>>(fsums, gf, bf, 1.0 / (double)(BB * NN), fscsh);
    fapply_stream<<<dim3(OUTC / 256, BB, 8), 256, 0, stream>>>(hbuf, fscsh, pmax);
    freduce<<<dim3(BB * OUTC / 256), 256, 0, stream>>>(pmax, out);
  } else {
    fstats_gemm<0><<<dim3(OUTC / 64, BB * NN / 64), 256, 0, stream>>>(F1f, F2f, F3f,
                                                                      Wf, fsums, nullptr);
    finalize_f<<<4, 256, 0, stream>>>(fsums, gf, bf, 1.0 / (double)(BB * NN), fscsh);
    fapply32<<<dim3(OUTC / 64, BB), 256, 0, stream>>>(F1f, F2f, F3f, Wf, fscsh, out);
  }
}